// Round 8
// baseline (23.983 us; speedup 1.0000x reference)
//
#include <hip/hip_runtime.h>
#include <math.h>

#define NUM_AUG 10
#define S_PAIRS 500
#define P 256

typedef __attribute__((ext_vector_type(8))) short bf16x8;
typedef __attribute__((ext_vector_type(16))) float f32x16;

// c_pair = 256/((20+1e-8)*0.01), c_single = 256/((10+1e-8)*0.01)
#define C_PAIR ((float)(256.0 / ((20.0 + 1e-8) * 0.01)))
#define C_SING ((float)(256.0 / ((10.0 + 1e-8) * 0.01)))

// Packed accumulator: bits[63:54] = block count, [53:27] = sum_pair (fixed
// point, scale 256), [26:0] = sum_single (scale 256). Partials are logdets of
// I + PSD => >= 0, < ~400 each; clamp 200000 => 500*200000 = 1e8 < 2^27.
#define CNT_SHIFT 54
#define SUM_MASK 0x7FFFFFFull
#define Q_SCALE 256.f

__device__ __forceinline__ unsigned short f2bf(float f) {
  unsigned u = __float_as_uint(f);
  unsigned r = (u + 0x7fffu + ((u >> 16) & 1u)) >> 16;  // RNE
  return (unsigned short)r;
}

// 1-thread init: zero the packed accumulator (replaces the costly fill node).
__global__ void init_kernel(unsigned long long* __restrict__ acc) {
  *acc = 0ull;
}

// One wave (64 threads) per pair. Each block contributes ONE relaxed 64-bit
// fetch_add carrying {count, quantized partial sums}. The block whose add is
// the 500th decodes the final sums from its return value (total order on a
// single address => no fences, no spin, bit-deterministic integer sums) and
// writes the outputs directly — no second heavy node, no full-grid drain.
__global__ __launch_bounds__(64) void fused_kernel(
    const float* __restrict__ X,
    const int* __restrict__ pairs,
    unsigned long long* __restrict__ acc,  // zeroed by init_kernel
    float* __restrict__ out) {
  // S staged as bf16, 32 rows x 512 bytes, XOR-swizzled: phys = row*512 + (cb ^ ((row&15)<<4))
  __shared__ uint4 Sb4[32 * 512 / 16];
  __shared__ float G[20][21];
  char* Sb = (char*)Sb4;

  const int s = blockIdx.x;
  const int lane = threadIdx.x;  // 0..63
  const int i0 = pairs[2 * s + 0] * NUM_AUG;
  const int j0 = pairs[2 * s + 1] * NUM_AUG;

  // ---- load 20 rows of X (f32) coalesced, convert to bf16, stage swizzled ----
#pragma unroll
  for (int r = 0; r < 20; ++r) {
    const int gr = (r < 10) ? (i0 + r) : (j0 + (r - 10));
    const float4 v = *((const float4*)(X + (size_t)gr * P) + lane);
    uint2 w;
    w.x = (unsigned)f2bf(v.x) | ((unsigned)f2bf(v.y) << 16);
    w.y = (unsigned)f2bf(v.z) | ((unsigned)f2bf(v.w) << 16);
    const int off = r * 512 + ((lane * 8) ^ ((r & 15) << 4));
    *(uint2*)(Sb + off) = w;
  }
  __syncthreads();

  // ---- G = S * S^T via 32x32x16 bf16 MFMA; a_frag == b_frag ----
  const int row = lane & 31;
  const int kg = lane >> 5;
  f32x16 acc0, acc1;
#pragma unroll
  for (int i = 0; i < 16; ++i) { acc0[i] = 0.f; acc1[i] = 0.f; }
#pragma unroll
  for (int kk = 0; kk < 16; ++kk) {
    const int cb = kk * 32 + kg * 16;  // byte col of this 8-elem k-slice
    const bf16x8 f = *(const bf16x8*)(Sb + row * 512 + (cb ^ ((row & 15) << 4)));
    if (kk & 1)
      acc1 = __builtin_amdgcn_mfma_f32_32x32x16_bf16(f, f, acc1, 0, 0, 0);
    else
      acc0 = __builtin_amdgcn_mfma_f32_32x32x16_bf16(f, f, acc0, 0, 0, 0);
  }
  // C/D layout (m74/m101): col = lane&31, row = (reg&3) + 8*(reg>>2) + 4*(lane>>5)
#pragma unroll
  for (int rg = 0; rg < 16; ++rg) {
    const int grow = (rg & 3) + 8 * (rg >> 2) + 4 * kg;
    if (grow < 20 && row < 20) G[grow][row] = acc0[rg] + acc1[rg];
  }
  __syncthreads();

  // ---- three register Choleskys in one wave, shuffle-based, barrier-free ----
  // lanes 0-31: M0 = I20 + C_PAIR*G (n=20); 32-47: M1 (G[0:10]); 48-63: M2 (G[10:20])
  const int grp = (lane < 32) ? 0 : (lane < 48) ? 1 : 2;
  const int base = (grp == 0) ? 0 : (grp == 1) ? 32 : 48;
  const int li = lane - base;
  const int n = (grp == 0) ? 20 : 10;
  const float cf = (grp == 0) ? C_PAIR : C_SING;
  const int r0 = (grp == 2) ? 10 : 0;

  float a[20];
#pragma unroll
  for (int k = 0; k < 20; ++k) {
    float g = 0.f;
    if (li < n && k < n) g = G[r0 + li][r0 + k];
    a[k] = cf * g + ((li == k) ? 1.f : 0.f);
  }

  float ld_acc = 0.f;
#pragma unroll
  for (int j = 0; j < 20; ++j) {
    const float dj = __shfl(a[j], base + j, 64);
    const float Ljj = sqrtf(dj);
    const float inv = 1.0f / Ljj;
    const float Lij = a[j] * inv;  // valid for li >= j; garbage elsewhere (never consumed)
    if (li == j && j < n) ld_acc += logf(Ljj);
#pragma unroll
    for (int k = j + 1; k < 20; ++k) {
      const float ck = __shfl(Lij, base + k, 64);
      if (k < n && li >= k) a[k] = fmaf(-Lij, ck, a[k]);
    }
  }

  // ---- wave reduce: ld_pair over lanes<32, ld_i+ld_j over lanes>=32 ----
  float vp = (lane < 32) ? ld_acc : 0.f;
  float vs = (lane >= 32) ? ld_acc : 0.f;
#pragma unroll
  for (int m = 1; m < 64; m <<= 1) {
    vp += __shfl_xor(vp, m, 64);
    vs += __shfl_xor(vs, m, 64);
  }

  // ---- one relaxed fetch_add: data + ticket in a single 64-bit word ----
  if (lane == 0) {
    unsigned qp = __float2uint_rn(2.f * vp * Q_SCALE);
    unsigned qs = __float2uint_rn(2.f * vs * Q_SCALE);
    qp = (qp > 200000u) ? 200000u : qp;  // field-overflow guard (pathological only)
    qs = (qs > 200000u) ? 200000u : qs;
    const unsigned long long add =
        (1ull << CNT_SHIFT) | ((unsigned long long)qp << 27) | (unsigned long long)qs;
    const unsigned long long old =
        __hip_atomic_fetch_add(acc, add, __ATOMIC_RELAXED, __HIP_MEMORY_SCOPE_AGENT);
    if ((old >> CNT_SHIFT) == (unsigned long long)(S_PAIRS - 1)) {
      const unsigned long long total = old + add;
      const float sp = (float)((total >> 27) & SUM_MASK) * (1.f / Q_SCALE);
      const float sij = (float)(total & SUM_MASK) * (1.f / Q_SCALE);
      const float mp = sp / (float)S_PAIRS;
      const float mij = sij / (float)S_PAIRS;
      const float ortho = mp - 0.5f * mij;
      out[0] = -0.01f * ortho;  // total_loss_empi = GAM3 * -ortho
      out[1] = mp;              // discrimn_loss_empi
      out[2] = mij;             // compress_loss_empi
      out[3] = ortho;           // compress_loss_empi_ortho
    }
  }
}

extern "C" void kernel_launch(void* const* d_in, const int* in_sizes, int n_in,
                              void* d_out, int out_size, void* d_ws, size_t ws_size,
                              hipStream_t stream) {
  const float* X = (const float*)d_in[0];
  // d_in[1] is y (int64) — unused by the loss values.
  const int* pairs = (const int*)d_in[2];
  float* out = (float*)d_out;

  unsigned long long* acc = (unsigned long long*)d_ws;  // single 8B word

  init_kernel<<<1, 1, 0, stream>>>(acc);
  fused_kernel<<<S_PAIRS, 64, 0, stream>>>(X, pairs, acc, out);
}

// Round 9
// 16.252 us; speedup vs baseline: 1.4757x; 1.4757x over previous
//
#include <hip/hip_runtime.h>
#include <math.h>

#define NUM_AUG 10
#define S_PAIRS 500
#define P 256

typedef __attribute__((ext_vector_type(8))) short bf16x8;
typedef __attribute__((ext_vector_type(16))) float f32x16;

// c_pair = 256/((20+1e-8)*0.01), c_single = 256/((10+1e-8)*0.01)
#define C_PAIR ((float)(256.0 / ((20.0 + 1e-8) * 0.01)))
#define C_SING ((float)(256.0 / ((10.0 + 1e-8) * 0.01)))

__device__ __forceinline__ unsigned short f2bf(float f) {
  unsigned u = __float_as_uint(f);
  unsigned r = (u + 0x7fffu + ((u >> 16) & 1u)) >> 16;  // RNE
  return (unsigned short)r;
}

// One wave (64 threads) per pair. Writes two partials per pair to ws.
__global__ __launch_bounds__(64) void pair_kernel(
    const float* __restrict__ X,
    const int* __restrict__ pairs,
    float* __restrict__ out2 /* [S_PAIRS][2] */) {
  // S staged as bf16, 32 rows x 512 bytes, XOR-swizzled: phys = row*512 + (cb ^ ((row&15)<<4))
  __shared__ uint4 Sb4[32 * 512 / 16];
  __shared__ float G[20][21];
  char* Sb = (char*)Sb4;

  const int s = blockIdx.x;
  const int lane = threadIdx.x;  // 0..63
  const int i0 = pairs[2 * s + 0] * NUM_AUG;
  const int j0 = pairs[2 * s + 1] * NUM_AUG;

  // ---- load 20 rows of X (f32) coalesced, convert to bf16, stage swizzled ----
#pragma unroll
  for (int r = 0; r < 20; ++r) {
    const int gr = (r < 10) ? (i0 + r) : (j0 + (r - 10));
    const float4 v = *((const float4*)(X + (size_t)gr * P) + lane);
    uint2 w;
    w.x = (unsigned)f2bf(v.x) | ((unsigned)f2bf(v.y) << 16);
    w.y = (unsigned)f2bf(v.z) | ((unsigned)f2bf(v.w) << 16);
    const int off = r * 512 + ((lane * 8) ^ ((r & 15) << 4));
    *(uint2*)(Sb + off) = w;
  }
  __syncthreads();

  // ---- G = S * S^T via 32x32x16 bf16 MFMA; a_frag == b_frag ----
  const int row = lane & 31;
  const int kg = lane >> 5;
  f32x16 acc0, acc1;
#pragma unroll
  for (int i = 0; i < 16; ++i) { acc0[i] = 0.f; acc1[i] = 0.f; }
#pragma unroll
  for (int kk = 0; kk < 16; ++kk) {
    const int cb = kk * 32 + kg * 16;  // byte col of this 8-elem k-slice
    const bf16x8 f = *(const bf16x8*)(Sb + row * 512 + (cb ^ ((row & 15) << 4)));
    if (kk & 1)
      acc1 = __builtin_amdgcn_mfma_f32_32x32x16_bf16(f, f, acc1, 0, 0, 0);
    else
      acc0 = __builtin_amdgcn_mfma_f32_32x32x16_bf16(f, f, acc0, 0, 0, 0);
  }
  // C/D layout (m74/m101): col = lane&31, row = (reg&3) + 8*(reg>>2) + 4*(lane>>5)
#pragma unroll
  for (int rg = 0; rg < 16; ++rg) {
    const int grow = (rg & 3) + 8 * (rg >> 2) + 4 * kg;
    if (grow < 20 && row < 20) G[grow][row] = acc0[rg] + acc1[rg];
  }
  __syncthreads();

  // ---- three register Choleskys in one wave, shuffle-based, barrier-free ----
  // lanes 0-31: M0 = I20 + C_PAIR*G (n=20); 32-47: M1 (G[0:10]); 48-63: M2 (G[10:20])
  const int grp = (lane < 32) ? 0 : (lane < 48) ? 1 : 2;
  const int base = (grp == 0) ? 0 : (grp == 1) ? 32 : 48;
  const int li = lane - base;
  const int n = (grp == 0) ? 20 : 10;
  const float cf = (grp == 0) ? C_PAIR : C_SING;
  const int r0 = (grp == 2) ? 10 : 0;

  float a[20];
#pragma unroll
  for (int k = 0; k < 20; ++k) {
    float g = 0.f;
    if (li < n && k < n) g = G[r0 + li][r0 + k];
    a[k] = cf * g + ((li == k) ? 1.f : 0.f);
  }

  float ld_acc = 0.f;
#pragma unroll
  for (int j = 0; j < 20; ++j) {
    const float dj = __shfl(a[j], base + j, 64);
    const float Ljj = sqrtf(dj);
    const float inv = 1.0f / Ljj;
    const float Lij = a[j] * inv;  // valid for li >= j; garbage elsewhere (never consumed)
    if (li == j && j < n) ld_acc += logf(Ljj);
#pragma unroll
    for (int k = j + 1; k < 20; ++k) {
      const float ck = __shfl(Lij, base + k, 64);
      if (k < n && li >= k) a[k] = fmaf(-Lij, ck, a[k]);
    }
  }

  // ---- wave reduce: ld_pair over lanes<32, ld_i+ld_j over lanes>=32 ----
  float vp = (lane < 32) ? ld_acc : 0.f;
  float vs = (lane >= 32) ? ld_acc : 0.f;
#pragma unroll
  for (int m = 1; m < 64; m <<= 1) {
    vp += __shfl_xor(vp, m, 64);
    vs += __shfl_xor(vs, m, 64);
  }
  if (lane == 0) {
    out2[2 * s + 0] = 2.f * vp;
    out2[2 * s + 1] = 2.f * vs;
  }
}

// Single-wave final reduce: float4 loads (2 pairs each), no LDS, no barriers.
__global__ __launch_bounds__(64) void reduce_kernel(
    const float* __restrict__ out2, float* __restrict__ out) {
  const int lane = threadIdx.x;
  float sp = 0.f, sij = 0.f;
#pragma unroll
  for (int t4 = lane; t4 < S_PAIRS / 2; t4 += 64) {  // 250 float4s = 500 pairs
    const float4 v = *(const float4*)(out2 + 4 * t4);
    sp += v.x + v.z;
    sij += v.y + v.w;
  }
#pragma unroll
  for (int m = 1; m < 64; m <<= 1) {
    sp += __shfl_xor(sp, m, 64);
    sij += __shfl_xor(sij, m, 64);
  }
  if (lane == 0) {
    const float mp = sp / (float)S_PAIRS;
    const float mij = sij / (float)S_PAIRS;
    const float ortho = mp - 0.5f * mij;
    out[0] = -0.01f * ortho;  // total_loss_empi = GAM3 * -ortho
    out[1] = mp;              // discrimn_loss_empi
    out[2] = mij;             // compress_loss_empi
    out[3] = ortho;           // compress_loss_empi_ortho
  }
}

extern "C" void kernel_launch(void* const* d_in, const int* in_sizes, int n_in,
                              void* d_out, int out_size, void* d_ws, size_t ws_size,
                              hipStream_t stream) {
  const float* X = (const float*)d_in[0];
  // d_in[1] is y (int64) — unused by the loss values.
  const int* pairs = (const int*)d_in[2];
  float* out = (float*)d_out;
  float* ws = (float*)d_ws;  // [S_PAIRS][2]

  pair_kernel<<<S_PAIRS, 64, 0, stream>>>(X, pairs, ws);
  reduce_kernel<<<1, 64, 0, stream>>>(ws, out);
}